// Round 1
// baseline (17233.458 us; speedup 1.0000x reference)
//
#include <hip/hip_runtime.h>
#include <math.h>

#define NN 1296          // 36*36 nodes
#define SL 37            // band slots = half-bandwidth+1
#define WROW 40          // LDS window row stride (pad)
#define PAD 40           // front/back pad for yw/ah/av

// ---------------- 3x3 SAME conv, NCHW/OIHW, co-tile of 8 per thread ----------
__global__ __launch_bounds__(256) void conv3x3_k(
    const float* __restrict__ in, const float* __restrict__ wgt,
    const float* __restrict__ bias, float* __restrict__ out,
    int Cin, int Cout, int relu)
{
  const int b  = blockIdx.z;
  const int co0 = blockIdx.y * 8;
  const int p  = blockIdx.x * 256 + threadIdx.x;
  if (p >= NN) return;
  const int py = p / 36, px = p % 36;
  float acc[8];
#pragma unroll
  for (int t = 0; t < 8; ++t) acc[t] = (co0 + t < Cout) ? bias[co0 + t] : 0.f;
  for (int ci = 0; ci < Cin; ++ci) {
    const float* __restrict__ inp = in + (size_t)(b * Cin + ci) * NN;
#pragma unroll
    for (int dy = 0; dy < 3; ++dy) {
      const int yy = py + dy - 1;
#pragma unroll
      for (int dx = 0; dx < 3; ++dx) {
        const int xx = px + dx - 1;
        const float v = ((unsigned)yy < 36u && (unsigned)xx < 36u) ? inp[yy * 36 + xx] : 0.f;
#pragma unroll
        for (int t = 0; t < 8; ++t) {
          // weight index is wave-uniform -> scalar loads
          const float w = (co0 + t < Cout)
              ? wgt[(((co0 + t) * Cin + ci) * 3 + dy) * 3 + dx] : 0.f;
          acc[t] = fmaf(v, w, acc[t]);
        }
      }
    }
  }
#pragma unroll
  for (int t = 0; t < 8; ++t) {
    if (co0 + t < Cout) {
      float r = acc[t];
      if (relu) r = fmaxf(r, 0.f);
      out[(size_t)(b * Cout + co0 + t) * NN + p] = r;
    }
  }
}

// ------------- per-node edge weights: wh (to x+1), wv (to y+1) ---------------
__global__ __launch_bounds__(256) void edgew_k(const float* __restrict__ feat,
    float* __restrict__ wh, float* __restrict__ wv)
{
  const int b = blockIdx.y;
  const int n = blockIdx.x * 256 + threadIdx.x;
  if (n >= NN) return;
  const int col = n % 36, row = n / 36;
  float sh = 0.f, sv = 0.f;
#pragma unroll
  for (int f = 0; f < 6; ++f) {
    const float* __restrict__ fp = feat + (size_t)(b * 6 + f) * NN;
    const float a = fp[n];
    if (col < 35) { const float d = a - fp[n + 1];  sh += d * d; }
    if (row < 35) { const float d = a - fp[n + 36]; sv += d * d; }
  }
  // w = exp(-S / sigma^2), sigma = 0.01
  wh[b * NN + n] = (col < 35) ? expf(-sh * 1e4f) : 0.f;
  wv[b * NN + n] = (row < 35) ? expf(-sv * 1e4f) : 0.f;
}

// ---------------- 9x { build banded A, Cholesky, fwd+back solve } ------------
// One block (64 threads = 1 wave) per (b, c) system. Band half-bandwidth 36.
__global__ __launch_bounds__(64) void gtv_k(
    const float* __restrict__ xf, const float* __restrict__ up,
    const float* __restrict__ whg, const float* __restrict__ wvg,
    float* __restrict__ Lg, float* __restrict__ out)
{
  const int sys  = blockIdx.x;         // 0..5
  const int b    = sys / 3, ch = sys % 3;
  const int lane = threadIdx.x;        // 0..63

  __shared__ float ys[NN];
  __shared__ float yw[PAD + NN + PAD];
  __shared__ float ah[PAD + NN + PAD];   // u * w_h / z_h  (0 at col==35 / OOB)
  __shared__ float av[PAD + NN + PAD];   // u * w_v / z_v  (0 at row==35 / OOB)
  __shared__ float rsv[NN];              // 1 / L[k][k]
  __shared__ float Win[SL][WROW];        // sliding band window (circular slots)
  __shared__ float colS[SL];
  __shared__ unsigned char tjt[672], tit[672];
  __shared__ float Lbuf[2][36 * SL + 4]; // back-sub row chunks (double buffer)

  float u = up[0];
  u = fminf(fmaxf(u, 0.001f), 1.0f);

  // triangle-update lookup tables: t -> (j in 1..36, i2 in 0..36-j), 666 entries
  for (int t = lane; t < 666; t += 64) {
    int acc = 0, jj = 1, ii = 0;
    for (int j = 1; j <= 36; ++j) {
      const int len = SL - j;
      if (t < acc + len) { jj = j; ii = t - acc; break; }
      acc += len;
    }
    tjt[t] = (unsigned char)jj; tit[t] = (unsigned char)ii;
  }
  for (int n = lane; n < NN; n += 64) ys[n] = xf[(size_t)(b * 3 + ch) * NN + n];
  for (int t = lane; t < PAD; t += 64) {
    yw[t] = 0.f; yw[PAD + NN + t] = 0.f;
    ah[t] = 0.f; ah[PAD + NN + t] = 0.f;
    av[t] = 0.f; av[PAD + NN + t] = 0.f;
  }
  __syncthreads();

  float* __restrict__ Ls = Lg + (size_t)sys * (NN * SL);

  for (int it = 0; it < 9; ++it) {
    // ---- u-scaled reweighted edge coefficients from current y ----
    for (int n = lane; n < NN; n += 64) {
      const int col = n % 36, row = n / 36;
      const float yn = ys[n];
      float a_h = 0.f, a_v = 0.f;
      if (col < 35) { const float z = fmaxf(fabsf(yn - ys[n + 1]),  0.01f); a_h = u * whg[b * NN + n] / z; }
      if (row < 35) { const float z = fmaxf(fabsf(yn - ys[n + 36]), 0.01f); a_v = u * wvg[b * NN + n] / z; }
      ah[PAD + n] = a_h; av[PAD + n] = a_v;
      yw[PAD + n] = yn;
    }
    __syncthreads();

    // ---- init first 37 band columns (analytic) ----
    if (lane < SL) {
      const int c = lane;
#pragma unroll
      for (int i = 0; i < SL; ++i) Win[c][i] = 0.f;
      Win[c][0]  = 1.f + ah[PAD + c - 1] + ah[PAD + c] + av[PAD + c - 36] + av[PAD + c];
      Win[c][1]  = -ah[PAD + c];
      Win[c][36] = -av[PAD + c];
    }
    __syncthreads();

    // ---- banded Cholesky with fused forward substitution ----
    for (int k = 0; k < NN; ++k) {
      const int s = k % SL;
      const float cv  = (lane < SL) ? Win[s][lane] : 0.f;
      const float d   = Win[s][0];            // broadcast read
      const float rs  = rsqrtf(d);            // d >= 1 always (I + uL, L PSD)
      const float cs  = cv * rs;
      const float ywk = yw[PAD + k];
      const float ck  = ywk * rs;
      if (lane < SL) colS[lane] = cs;
      if (lane == 0) { rsv[k] = rs; yw[PAD + k] = ck; }
      __syncthreads();
      // forward update: yw[k+i] -= L[k+i][k] * c_k
      if (lane >= 1 && lane < SL) yw[PAD + k + lane] -= colS[lane] * ck;
      // stream L out in row-major band layout: Lrow[r][36-(r-k)] = L[r][k]
      if (lane < SL && k + lane < NN) Ls[(size_t)(k + lane) * SL + (36 - lane)] = cs;
      // rank-1 trailing-band update, 666 entries over 11 chunks
#pragma unroll
      for (int q = 0; q < 11; ++q) {
        const int t = lane + q * 64;
        if (t < 666) {
          const int j = tjt[t], i2 = tit[t];
          int sj = s + j; if (sj >= SL) sj -= SL;
          Win[sj][i2] -= colS[i2 + j] * colS[j];
        }
      }
      // bring in column k+37 (slot s just freed)
      const int nc = k + SL;
      if (nc < NN && lane < SL) {
        float e = 0.f;
        if (lane == 0)
          e = 1.f + ah[PAD + nc - 1] + ah[PAD + nc] + av[PAD + nc - 36] + av[PAD + nc];
        else if (lane == 1)  e = -ah[PAD + nc];
        else if (lane == 36) e = -av[PAD + nc];
        Win[s][lane] = e;
      }
      __syncthreads();
    }

    // ---- back substitution (L^T x = c), chunked row prefetch ----
    // chunks of 36 rows, descending; register-staged prefetch overlaps HBM/L2 latency
    int pb = 0;
    for (int t = lane; t < 36 * SL; t += 64) Lbuf[0][t] = Ls[(size_t)(NN - 36) * SL + t];
    __syncthreads();
    for (int cindex = 0; cindex < 36; ++cindex) {
      const int base = NN - 36 * (cindex + 1);
      float pre[21];
      const bool havenext = (cindex + 1 < 36);
      if (havenext) {
        const int nbase = base - 36;
#pragma unroll
        for (int q = 0; q < 21; ++q) {
          const int t = lane + q * 64;
          pre[q] = (t < 36 * SL) ? Ls[(size_t)nbase * SL + t] : 0.f;
        }
      }
      for (int r = 35; r >= 0; --r) {
        const int k = base + r;
        const float xk = yw[PAD + k] * rsv[k];
        const float lv = (lane < 36) ? Lbuf[pb][r * SL + lane] : 0.f;
        if (lane == 0) yw[PAD + k] = xk;
        if (lane < 36) {
          const int i = 36 - lane;              // i in 1..36
          yw[PAD + k - i] -= lv * xk;           // k-i<0 lands in zeroed front pad
        }
        __syncthreads();
      }
      if (havenext) {
#pragma unroll
        for (int q = 0; q < 21; ++q) {
          const int t = lane + q * 64;
          if (t < 36 * SL) Lbuf[pb ^ 1][t] = pre[q];
        }
      }
      pb ^= 1;
      __syncthreads();
    }

    // ---- commit x as next y ----
    for (int n = lane; n < NN; n += 64) ys[n] = yw[PAD + n];
    __syncthreads();
  }

  for (int n = lane; n < NN; n += 64) out[(size_t)(b * 3 + ch) * NN + n] = ys[n];
}

// ----------------------------------------------------------------------------
extern "C" void kernel_launch(void* const* d_in, const int* in_sizes, int n_in,
                              void* d_out, int out_size, void* d_ws, size_t ws_size,
                              hipStream_t stream) {
  const float* xf     = (const float*)d_in[0];   // [2,3,36,36]
  const float* up     = (const float*)d_in[1];   // [1]
  // d_in[2] = H (unused; graph structure is hardcoded)
  const float* cw_in  = (const float*)d_in[3];   // [32,3,3,3]
  const float* b_in   = (const float*)d_in[4];   // [32]
  const float* cw_mid = (const float*)d_in[5];   // [5,32,32,3,3]
  const float* b_mid  = (const float*)d_in[6];   // [5,32]
  const float* cw_out = (const float*)d_in[7];   // [6,32,3,3]
  const float* b_out  = (const float*)d_in[8];   // [6]
  // d_in[9], d_in[10] = idx0/idx1 (unused)

  float* ws   = (float*)d_ws;
  float* hb0  = ws;                  // 2*32*1296 = 82944
  float* hb1  = hb0 + 82944;         // 82944
  float* feat = hb1 + 82944;         // 2*6*1296 = 15552
  float* wh   = feat + 15552;        // 2*1296
  float* wv   = wh + 2592;           // 2*1296
  float* Lg   = wv + 2592;           // 6*1296*37 = 287712

  const dim3 cgrid(6, 4, 2), cblk(256);
  conv3x3_k<<<cgrid, cblk, 0, stream>>>(xf, cw_in, b_in, hb0, 3, 32, 1);
  const float* src = hb0; float* dst = hb1;
  for (int i = 0; i < 5; ++i) {
    conv3x3_k<<<cgrid, cblk, 0, stream>>>(src, cw_mid + i * 9216, b_mid + i * 32,
                                          dst, 32, 32, 1);
    const float* t = dst; dst = (float*)src; src = t;
  }
  // after 5 mid layers the latest output is in `src`
  conv3x3_k<<<dim3(6, 1, 2), cblk, 0, stream>>>(src, cw_out, b_out, feat, 32, 6, 0);

  edgew_k<<<dim3(6, 2), cblk, 0, stream>>>(feat, wh, wv);

  gtv_k<<<dim3(6), dim3(64), 0, stream>>>(xf, up, wh, wv, Lg, (float*)d_out);
}

// Round 2
// 9211.349 us; speedup vs baseline: 1.8709x; 1.8709x over previous
//
#include <hip/hip_runtime.h>
#include <math.h>

#define NN 1296          // 36*36 nodes
#define LWAIT() asm volatile("s_waitcnt lgkmcnt(0)" ::: "memory")
#define VWAIT() asm volatile("s_waitcnt vmcnt(0) lgkmcnt(0)" ::: "memory")

// ---------------- 3x3 SAME conv, NCHW/OIHW, co-tile of 8 per thread ----------
__global__ __launch_bounds__(256) void conv3x3_k(
    const float* __restrict__ in, const float* __restrict__ wgt,
    const float* __restrict__ bias, float* __restrict__ out,
    int Cin, int Cout, int relu)
{
  const int b  = blockIdx.z;
  const int co0 = blockIdx.y * 8;
  const int p  = blockIdx.x * 256 + threadIdx.x;
  if (p >= NN) return;
  const int py = p / 36, px = p % 36;
  float acc[8];
#pragma unroll
  for (int t = 0; t < 8; ++t) acc[t] = (co0 + t < Cout) ? bias[co0 + t] : 0.f;
  for (int ci = 0; ci < Cin; ++ci) {
    const float* __restrict__ inp = in + (size_t)(b * Cin + ci) * NN;
#pragma unroll
    for (int dy = 0; dy < 3; ++dy) {
      const int yy = py + dy - 1;
#pragma unroll
      for (int dx = 0; dx < 3; ++dx) {
        const int xx = px + dx - 1;
        const float v = ((unsigned)yy < 36u && (unsigned)xx < 36u) ? inp[yy * 36 + xx] : 0.f;
#pragma unroll
        for (int t = 0; t < 8; ++t) {
          const float w = (co0 + t < Cout)
              ? wgt[(((co0 + t) * Cin + ci) * 3 + dy) * 3 + dx] : 0.f;
          acc[t] = fmaf(v, w, acc[t]);
        }
      }
    }
  }
#pragma unroll
  for (int t = 0; t < 8; ++t) {
    if (co0 + t < Cout) {
      float r = acc[t];
      if (relu) r = fmaxf(r, 0.f);
      out[(size_t)(b * Cout + co0 + t) * NN + p] = r;
    }
  }
}

// ------------- per-node edge weights: wh (to x+1), wv (to y+1) ---------------
__global__ __launch_bounds__(256) void edgew_k(const float* __restrict__ feat,
    float* __restrict__ wh, float* __restrict__ wv)
{
  const int b = blockIdx.y;
  const int n = blockIdx.x * 256 + threadIdx.x;
  if (n >= NN) return;
  const int col = n % 36, row = n / 36;
  float sh = 0.f, sv = 0.f;
#pragma unroll
  for (int f = 0; f < 6; ++f) {
    const float* __restrict__ fp = feat + (size_t)(b * 6 + f) * NN;
    const float a = fp[n];
    if (col < 35) { const float d = a - fp[n + 1];  sh += d * d; }
    if (row < 35) { const float d = a - fp[n + 36]; sv += d * d; }
  }
  wh[b * NN + n] = (col < 35) ? expf(-sh * 1e4f) : 0.f;
  wv[b * NN + n] = (row < 35) ? expf(-sv * 1e4f) : 0.f;
}

// ---------------- 9x { build banded A, Cholesky, fwd+back solve } ------------
// One wave per (b,c) system. Wave-synchronous: NO __syncthreads anywhere.
// Band half-bandwidth 36. Augmented window: row 37 = RHS (fused forward sub).
__global__ __launch_bounds__(64) void gtv_k(
    const float* __restrict__ xf, const float* __restrict__ up,
    const float* __restrict__ whg, const float* __restrict__ wvg,
    float* __restrict__ Lg, float* __restrict__ out)
{
  const int sys  = blockIdx.x;         // 0..5
  const int b    = sys / 3, ch = sys % 3;
  const int lane = threadIdx.x;        // 0..63

  __shared__ float win[64 * 64];       // circular band window, 16 KB, pow2 addressing
  __shared__ float csbuf[64];          // current scaled column, lane-indexed
  __shared__ float ysl[NN + 40];       // current y (solution of prev iter)
  __shared__ float xsv[NN + 40];       // forward-solved RHS c_k
  __shared__ float rsv[NN + 40];       // 1/sqrt(diag pivot)
  __shared__ float ahp[NN + 80];       // front pad 40: u*w_h/z_h
  __shared__ float avp[NN + 80];       // front pad 40: u*w_v/z_v
  __shared__ float diagv[NN];          // 1 + ah[n-1]+ah[n]+av[n-36]+av[n]

  float u = up[0];
  u = fminf(fmaxf(u, 0.001f), 1.0f);

  // ---- per-lane constants ----
  const bool is0 = (lane == 0), is1 = (lane == 1), is36 = (lane == 36), is37 = (lane == 37);
  const bool isLs = (lane < 37);
  const int  selB  = (lane <= 35) ? (lane + 1) * 4 : (is37 ? 37 * 4 : 63 * 4);
  const float m36f = (lane <= 35 || is37) ? 1.f : 0.f;
  const int  lsOff = lane * 36 + 36;            // lane*37 + 36 - lane
  float* xrp = is37 ? xsv : rsv;                // combined xs/rsv store target

  // ---- triangle tables (j=2..36 band + RHS entries; 665 real, rest dumped) ----
  int preW[11], sA[11], sB[11];
#pragma unroll
  for (int q = 0; q < 11; ++q) {
    const int t = lane + q * 64;
    int jj = 2, off = 63, srcA = 63, srcB = 63;
    if (t < 665) {
      int acc = 0;
      for (int j = 2; j <= 36; ++j) {
        const int len = 38 - j;                  // (37-j) band + 1 RHS
        if (t < acc + len) {
          const int e = t - acc;
          jj = j; srcB = j;
          if (e < 37 - j) { off = e;  srcA = e + j; }
          else            { off = 37; srcA = 37;    }
          break;
        }
        acc += len;
      }
    }
    preW[q] = jj * 64 + off;                     // word offset added to kW
    sA[q] = srcA; sB[q] = srcB;
  }

  // ---- load y0 = xf; zero pads ----
  for (int n = lane; n < NN; n += 64) ysl[n] = xf[(size_t)(b * 3 + ch) * NN + n];
  for (int t = lane; t < 40; t += 64) {
    ysl[NN + t] = 0.f; xsv[NN + t] = 0.f; rsv[NN + t] = 0.f;
    ahp[t] = 0.f; avp[t] = 0.f;
  }
  LWAIT();

  const float* __restrict__ whB = whg + b * NN;
  const float* __restrict__ wvB = wvg + b * NN;
  float* __restrict__ Ls = Lg + (size_t)sys * ((NN + 80) * 37);

  for (int it = 0; it < 9; ++it) {
    // ---- phase 1: reweighted edge coefficients from current y ----
    for (int n = lane; n < NN; n += 64) {
      const float yn = ysl[n];
      const float zh = fmaxf(fabsf(yn - ysl[n + 1]),  0.01f);
      const float zv = fmaxf(fabsf(yn - ysl[n + 36]), 0.01f);
      ahp[40 + n] = u * whB[n] / zh;
      avp[40 + n] = u * wvB[n] / zv;
    }
    LWAIT();
    for (int n = lane; n < NN; n += 64)
      diagv[n] = 1.f + ahp[40 + n - 1] + ahp[40 + n] + avp[40 + n - 36] + avp[40 + n];
    LWAIT();

    // ---- phase 2: insert columns 0..36 (full 64-lane overwrite per slot) ----
    for (int c = 0; c < 37; ++c) {
      const float dg = diagv[c], a1 = ahp[40 + c], a36 = avp[40 + c], yv = ysl[c];
      float v = 0.f;
      v = is0  ?  dg  : v;
      v = is1  ? -a1  : v;
      v = is36 ? -a36 : v;
      v = is37 ?  yv  : v;
      win[c * 64 + lane] = v;
    }
    LWAIT();

    float cv = win[lane];                        // column 0 (augmented)
    int kW = 0;                                  // (k*64) & 4095
    int kL37 = 0;                                // k*37

    // ---- phase 3: banded Cholesky, fused forward sub, wave-synchronous ----
    for (int k = 0; k < NN; ++k) {
      LWAIT();                                   // drain prev step's LDS writes
      const float cpre = win[((kW + 64) & 4095) + lane];   // col k+1 pre-update
      const float rsf  = rsqrtf(__int_as_float(
          __builtin_amdgcn_readfirstlane(__float_as_int(cv))));
      const float cs   = cv * rsf;               // scaled column (lane37 = c_k)
      csbuf[lane] = cs;
      const float csb  = __int_as_float(
          __builtin_amdgcn_ds_bpermute(selB, __float_as_int(cs)));   // cs[lane+1]
      const float cs1  = __int_as_float(
          __builtin_amdgcn_readlane(__float_as_int(cs), 1));

      // off-critical-path stores
      if (isLs) Ls[kL37 + lsOff] = cs;           // L column, row-major band
      if (is0 | is37) xrp[k] = is37 ? cs : rsf;  // c_k (lane37) / 1/sqrt(d) (lane0)

      // rank-1 trailing update for j=2..36 (+RHS), 665 entries, 11 chunks
      float Aa[11], Bb[11];
#pragma unroll
      for (int q = 0; q < 11; ++q) { Aa[q] = csbuf[sA[q]]; Bb[q] = csbuf[sB[q]]; }
#pragma unroll
      for (int q = 0; q < 11; ++q) {
        const int wi = (kW + preW[q]) & 4095;
        win[wi] = win[wi] - Aa[q] * Bb[q];
      }

      // insert column k+37 into freed slot
      const int nc = k + 37;
      if (nc < NN) {
        const float dg = diagv[nc], a1 = ahp[40 + nc], a36 = avp[40 + nc], yv = ysl[nc];
        float v = 0.f;
        v = is0  ?  dg  : v;
        v = is1  ? -a1  : v;
        v = is36 ? -a36 : v;
        v = is37 ?  yv  : v;
        win[((kW + 37 * 64) & 4095) + lane] = v;
      }

      // register-carried j=1 update of column k+1
      cv = cpre - (csb * m36f) * cs1;
      kW = (kW + 64) & 4095;
      kL37 += 37;
    }

    // ---- phase 4: back substitution (L^T x = c), register-chunked ----
    VWAIT();                                     // L stores -> our loads
    float xcur[36];
#pragma unroll
    for (int m = 0; m < 36; ++m) xcur[m] = 0.f;

    for (int cb = 35; cb >= 0; --cb) {
      const int base = cb * 36;
      float raw[71];
      // raw[i-1] = Ls[(base+i)*37 + 36-i + lane], i=1..71 (coalesced, masked at use)
#pragma unroll
      for (int i = 1; i <= 71; ++i)
        raw[i - 1] = Ls[(size_t)(base + i) * 37 + (36 - i) + lane];

      float w   = xsv[base + lane];
      const float rsB = rsv[base + lane];
      // cross-chunk updates from previously solved 36 rows above
#pragma unroll
      for (int m = 0; m < 36; ++m) {
        const float Lv = (lane >= m) ? raw[35 + m] : 0.f;
        w -= Lv * xcur[m];
      }
      float myx = 0.f;
#pragma unroll
      for (int r = 35; r >= 0; --r) {
        const float t  = w * rsB;
        const float xr = __int_as_float(
            __builtin_amdgcn_readlane(__float_as_int(t), r));
        myx = (lane == r) ? t : myx;
        if (r > 0) {
          const float Lv = (lane < r) ? raw[r - 1] : 0.f;
          w -= Lv * xr;
        }
        xcur[r] = xr;
      }
      if (lane < 36) ysl[base + lane] = myx;     // x becomes next iteration's y
    }
    LWAIT();
  }

  for (int n = lane; n < NN; n += 64) out[(size_t)(b * 3 + ch) * NN + n] = ysl[n];
}

// ----------------------------------------------------------------------------
extern "C" void kernel_launch(void* const* d_in, const int* in_sizes, int n_in,
                              void* d_out, int out_size, void* d_ws, size_t ws_size,
                              hipStream_t stream) {
  const float* xf     = (const float*)d_in[0];   // [2,3,36,36]
  const float* up     = (const float*)d_in[1];   // [1]
  const float* cw_in  = (const float*)d_in[3];   // [32,3,3,3]
  const float* b_in   = (const float*)d_in[4];   // [32]
  const float* cw_mid = (const float*)d_in[5];   // [5,32,32,3,3]
  const float* b_mid  = (const float*)d_in[6];   // [5,32]
  const float* cw_out = (const float*)d_in[7];   // [6,32,3,3]
  const float* b_out  = (const float*)d_in[8];   // [6]

  float* ws   = (float*)d_ws;
  float* hb0  = ws;                   // 2*32*1296 = 82944
  float* hb1  = hb0 + 82944;          // 82944
  float* feat = hb1 + 82944;          // 2*6*1296 = 15552
  float* wh   = feat + 15552;         // 2*1296
  float* wv   = wh + 2592;            // 2*1296
  float* Lg   = wv + 2592;            // 6*(1296+80)*37 = 305472

  const dim3 cgrid(6, 4, 2), cblk(256);
  conv3x3_k<<<cgrid, cblk, 0, stream>>>(xf, cw_in, b_in, hb0, 3, 32, 1);
  const float* src = hb0; float* dst = hb1;
  for (int i = 0; i < 5; ++i) {
    conv3x3_k<<<cgrid, cblk, 0, stream>>>(src, cw_mid + i * 9216, b_mid + i * 32,
                                          dst, 32, 32, 1);
    const float* t = dst; dst = (float*)src; src = t;
  }
  conv3x3_k<<<dim3(6, 1, 2), cblk, 0, stream>>>(src, cw_out, b_out, feat, 32, 6, 0);

  edgew_k<<<dim3(6, 2), cblk, 0, stream>>>(feat, wh, wv);

  gtv_k<<<dim3(6), dim3(64), 0, stream>>>(xf, up, wh, wv, Lg, (float*)d_out);
}